// Round 3
// baseline (331.324 us; speedup 1.0000x reference)
//
#include <hip/hip_runtime.h>

#define N_NODES 50000
#define N_EDGES 800000
#define N_GRAPHS 256
#define D_FEAT 96
#define HIDDEN 32

#define NB 196        // bins: bin = dst >> 8 (dst < 50000 -> bin <= 195)
#define CAPB 8192     // per-bin capacity; mean 4082, sigma ~64 -> 64-sigma margin
#define PA_BLOCKS 128
#define PA_CHUNK 6250 // 128 * 6250 = 800000 exactly
#define GWIN 8        // pooled-graph LDS window per 256-node bin (spans <= ~3 graphs)

// ---------------------------------------------------------------------------
// Kernel 0: init cursors (gcursor[b] = b*CAPB) and zero sums/counts.
__global__ void k_init(int* __restrict__ gcursor, float* __restrict__ sums,
                       float* __restrict__ counts) {
    int t = blockIdx.x * blockDim.x + threadIdx.x;
    if (t < NB) gcursor[t] = t * CAPB;
    if (t < N_GRAPHS * HIDDEN) sums[t] = 0.f;
    if (t < N_GRAPHS) counts[t] = 0.f;
}

// ---------------------------------------------------------------------------
// Kernel 1: y = x @ W1   (32 lanes per node, lane = hidden feature)
__global__ void k_xw1(const float* __restrict__ x, const float* __restrict__ W1,
                      float* __restrict__ y) {
    int gid = blockIdx.x * blockDim.x + threadIdx.x;
    int node = gid >> 5;
    int f = gid & 31;
    const float* xr = x + (size_t)node * D_FEAT;
    float acc = 0.f;
#pragma unroll
    for (int k = 0; k < D_FEAT; ++k)
        acc = fmaf(xr[k], W1[k * HIDDEN + f], acc);
    y[gid] = acc;
}

// ---------------------------------------------------------------------------
// Kernel 2: partition edges into NB bins by dst>>8.
// Two-pass block-local histogram -> 1 global atomic per (block,bin) -> packed write.
__global__ void __launch_bounds__(256)
k_partition(const int* __restrict__ src, const int* __restrict__ dst,
            int* __restrict__ gcursor, unsigned int* __restrict__ binned) {
    __shared__ int hist[NB];
    __shared__ int base[NB];
    int tid = threadIdx.x;
    for (int i = tid; i < NB; i += 256) hist[i] = 0;
    __syncthreads();

    int e0 = blockIdx.x * PA_CHUNK;
    int e1 = e0 + PA_CHUNK;
    if (e1 > N_EDGES) e1 = N_EDGES;

    for (int e = e0 + tid; e < e1; e += 256)
        atomicAdd(&hist[dst[e] >> 8], 1);
    __syncthreads();

    for (int i = tid; i < NB; i += 256) {
        int c = hist[i];
        base[i] = (c > 0) ? atomicAdd(&gcursor[i], c) : 0;
        hist[i] = 0;   // reuse as intra-block cursor
    }
    __syncthreads();

    for (int e = e0 + tid; e < e1; e += 256) {
        int d = dst[e];
        int b = d >> 8;
        int pos = base[b] + atomicAdd(&hist[b], 1);
        if (pos < (b + 1) * CAPB)   // capacity guard (statistically never)
            binned[pos] = (unsigned)src[e] | ((unsigned)(d & 255) << 16);
    }
}

// ---------------------------------------------------------------------------
// Kernel 3: per-bin LDS aggregation + MLP + mean-pool. One 512-thr block per bin.
__global__ void __launch_bounds__(512)
k_binagg_mlp_pool(const unsigned int* __restrict__ binned, const int* __restrict__ gcursor,
                  const float* __restrict__ y, const int* __restrict__ batch,
                  const float* __restrict__ b1, const float* __restrict__ W2,
                  const float* __restrict__ b2,
                  float* __restrict__ sums, float* __restrict__ counts) {
    __shared__ float agg[256 * HIDDEN];      // 32 KB
    __shared__ float w2s[HIDDEN * HIDDEN];   // 4 KB
    __shared__ float accs[GWIN * HIDDEN];    // 1 KB
    __shared__ float cnts[GWIN];

    int tid = threadIdx.x;
    int bin = blockIdx.x;
    for (int i = tid; i < 256 * HIDDEN; i += 512) agg[i] = 0.f;
    for (int i = tid; i < HIDDEN * HIDDEN; i += 512) w2s[i] = W2[i];
    if (tid < GWIN * HIDDEN) accs[tid] = 0.f;
    if (tid < GWIN) cnts[tid] = 0.f;
    __syncthreads();

    int ecount = gcursor[bin] - bin * CAPB;
    if (ecount > CAPB) ecount = CAPB;
    const unsigned int* eb = binned + (size_t)bin * CAPB;

    int g = tid >> 5;     // half-wave group 0..15 (32 lanes each)
    int f = tid & 31;     // feature lane

    // edge aggregation: 16 groups x 4 edges in flight = 64 edges / iteration
    for (int e = g * 4; e < ecount; e += 64) {
        int rem = ecount - e;
        unsigned p0 = eb[e];
        unsigned p1 = (rem > 1) ? eb[e + 1] : p0;
        unsigned p2 = (rem > 2) ? eb[e + 2] : p0;
        unsigned p3 = (rem > 3) ? eb[e + 3] : p0;
        float a0 = y[(size_t)(p0 & 0xFFFF) * HIDDEN + f];
        float a1 = y[(size_t)(p1 & 0xFFFF) * HIDDEN + f];
        float a2 = y[(size_t)(p2 & 0xFFFF) * HIDDEN + f];
        float a3 = y[(size_t)(p3 & 0xFFFF) * HIDDEN + f];
        atomicAdd(&agg[(p0 >> 16) * HIDDEN + f], a0);            // ds_add_f32, bank=f
        if (rem > 1) atomicAdd(&agg[(p1 >> 16) * HIDDEN + f], a1);
        if (rem > 2) atomicAdd(&agg[(p2 >> 16) * HIDDEN + f], a2);
        if (rem > 3) atomicAdd(&agg[(p3 >> 16) * HIDDEN + f], a3);
    }
    __syncthreads();

    int node0 = bin << 8;
    int nn = N_NODES - node0; if (nn > 256) nn = 256;
    int gfirst = batch[node0];

    // stage 1: h1 = ReLU(agg + y_self + b1), in place
    for (int ln = g; ln < nn; ln += 16) {
        float h1 = agg[ln * HIDDEN + f] + y[(size_t)(node0 + ln) * HIDDEN + f] + b1[f];
        agg[ln * HIDDEN + f] = fmaxf(h1, 0.f);
    }
    __syncthreads();

    // stage 2: h = ReLU(h1 @ W2 + b2), accumulate pooled sums in LDS window
    for (int ln = g; ln < nn; ln += 16) {
        float h2 = b2[f];
#pragma unroll
        for (int k = 0; k < HIDDEN; ++k)
            h2 = fmaf(agg[ln * HIDDEN + k], w2s[k * HIDDEN + f], h2);
        float h = fmaxf(h2, 0.f);
        int gr = batch[node0 + ln];
        int b = gr - gfirst;
        if (b < GWIN) {
            atomicAdd(&accs[b * HIDDEN + f], h);
            if (f == 0) atomicAdd(&cnts[b], 1.f);
        } else {
            atomicAdd(&sums[(size_t)gr * HIDDEN + f], h);
            if (f == 0) atomicAdd(&counts[gr], 1.f);
        }
    }
    __syncthreads();

    for (int i = tid; i < GWIN * HIDDEN; i += 512) {
        float v = accs[i];
        if (v != 0.f) atomicAdd(&sums[(size_t)gfirst * HIDDEN + i], v);
    }
    if (tid < GWIN) {
        float c = cnts[tid];
        if (c != 0.f) atomicAdd(&counts[gfirst + tid], c);
    }
}

// ---------------------------------------------------------------------------
// Kernel 4: out[g] = (sums[g]/max(counts[g],1)) @ Wc + bc
__global__ void k_out(const float* __restrict__ sums, const float* __restrict__ counts,
                      const float* __restrict__ Wc, const float* __restrict__ bc,
                      float* __restrict__ out) {
    int g = threadIdx.x;
    if (g >= N_GRAPHS) return;
    float inv = 1.f / fmaxf(counts[g], 1.f);
    float o0 = bc[0], o1 = bc[1];
#pragma unroll
    for (int k = 0; k < HIDDEN; ++k) {
        float p = sums[(size_t)g * HIDDEN + k] * inv;
        o0 = fmaf(p, Wc[k * 2 + 0], o0);
        o1 = fmaf(p, Wc[k * 2 + 1], o1);
    }
    out[g * 2 + 0] = o0;
    out[g * 2 + 1] = o1;
}

// ---------------------------------------------------------------------------
extern "C" void kernel_launch(void* const* d_in, const int* in_sizes, int n_in,
                              void* d_out, int out_size, void* d_ws, size_t ws_size,
                              hipStream_t stream) {
    const float* x     = (const float*)d_in[0];
    const int*   ei    = (const int*)d_in[1];   // [2, N_EDGES]: src row then dst row
    const int*   batch = (const int*)d_in[2];
    const float* W1    = (const float*)d_in[3];
    const float* b1    = (const float*)d_in[4];
    const float* W2    = (const float*)d_in[5];
    const float* b2    = (const float*)d_in[6];
    const float* Wc    = (const float*)d_in[7];
    const float* bc    = (const float*)d_in[8];
    float* out = (float*)d_out;

    // Workspace layout (byte offsets):
    //   0        gcursor  NB int          (1024 B padded)
    //   1024     sums     8192 f          (32768 B)
    //   33792    counts   256 f           (1024 B)
    //   34816    binned   NB*CAPB u32     (6422528 B)
    //   6457344  y        1.6M f          (6400000 B)
    // total ~12.86 MB
    char* ws = (char*)d_ws;
    int*          gcursor = (int*)ws;
    float*        sums    = (float*)(ws + 1024);
    float*        counts  = (float*)(ws + 33792);
    unsigned int* binned  = (unsigned int*)(ws + 34816);
    float*        y       = (float*)(ws + 6457344);

    k_init<<<(N_GRAPHS * HIDDEN + 255) / 256, 256, 0, stream>>>(gcursor, sums, counts);

    k_xw1<<<N_NODES * HIDDEN / 256, 256, 0, stream>>>(x, W1, y);

    k_partition<<<PA_BLOCKS, 256, 0, stream>>>(ei, ei + N_EDGES, gcursor, binned);

    k_binagg_mlp_pool<<<NB, 512, 0, stream>>>(binned, gcursor, y, batch,
                                              b1, W2, b2, sums, counts);

    k_out<<<1, 256, 0, stream>>>(sums, counts, Wc, bc, out);
}

// Round 4
// 171.244 us; speedup vs baseline: 1.9348x; 1.9348x over previous
//
#include <hip/hip_runtime.h>

#define N_NODES 50000
#define N_EDGES 800000
#define N_GRAPHS 256
#define D_FEAT 96
#define HIDDEN 32

#define NB 196        // bins: bin = dst >> 8 (dst < 50000 -> bin <= 195)
#define CAPB 8192     // per-bin slot capacity in global binned[]
#define PB 256        // partition blocks
#define PCHUNK 3125   // 256 * 3125 = 800000 exactly
#define GWIN 16       // pooled-graph LDS window per 256-node bin
#define LCAP 6144     // per-bin LDS edge-list capacity (actual ~4082 +- 64)

// ---------------------------------------------------------------------------
// Kernel 1: y = x @ W1, with all small-buffer init folded in (first blocks).
__global__ void k_xw1(const float* __restrict__ x, const float* __restrict__ W1,
                      float* __restrict__ y, int* __restrict__ gcursor,
                      float* __restrict__ sums, float* __restrict__ counts) {
    int gid = blockIdx.x * blockDim.x + threadIdx.x;
    if (gid < NB) gcursor[gid] = gid * CAPB;
    if (gid < N_GRAPHS * HIDDEN) sums[gid] = 0.f;
    if (gid < N_GRAPHS) counts[gid] = 0.f;
    int node = gid >> 5;
    int f = gid & 31;
    const float* xr = x + (size_t)node * D_FEAT;
    float acc = 0.f;
#pragma unroll
    for (int k = 0; k < D_FEAT; ++k)
        acc = fmaf(xr[k], W1[k * HIDDEN + f], acc);
    y[gid] = acc;
}

// ---------------------------------------------------------------------------
// Kernel 2: partition edges into NB bins by dst>>8.
// Block-local LDS histogram -> one global atomic per (block,bin) -> clustered
// packed writes (runs of ~12 contiguous u32 per (block,bin)).
__global__ void __launch_bounds__(256)
k_partition(const int* __restrict__ src, const int* __restrict__ dst,
            int* __restrict__ gcursor, unsigned int* __restrict__ binned) {
    __shared__ int hist[NB];
    __shared__ int base[NB];
    int tid = threadIdx.x;
    for (int i = tid; i < NB; i += 256) hist[i] = 0;
    __syncthreads();

    int e0 = blockIdx.x * PCHUNK;
    int e1 = e0 + PCHUNK;

    for (int e = e0 + tid; e < e1; e += 256)
        atomicAdd(&hist[dst[e] >> 8], 1);
    __syncthreads();

    for (int i = tid; i < NB; i += 256) {
        int c = hist[i];
        base[i] = (c > 0) ? atomicAdd(&gcursor[i], c) : 0;
        hist[i] = 0;   // reuse as intra-block cursor
    }
    __syncthreads();

    for (int e = e0 + tid; e < e1; e += 256) {
        int d = dst[e];
        int b = d >> 8;
        int pos = base[b] + atomicAdd(&hist[b], 1);
        if (pos < (b + 1) * CAPB)   // capacity guard (statistically never taken)
            binned[pos] = (unsigned)src[e] | ((unsigned)(d & 255) << 16);
    }
}

// ---------------------------------------------------------------------------
// Kernel 3: per-bin counting-sort to CSR in LDS, register-accumulated gather,
// MLP via intra-group shuffles, windowed mean-pool. One 1024-thr block per bin.
__global__ void __launch_bounds__(1024)
k_agg_mlp_pool(const unsigned int* __restrict__ binned, const int* __restrict__ gcursor,
               const float* __restrict__ y, const int* __restrict__ batch,
               const float* __restrict__ b1, const float* __restrict__ W2,
               const float* __restrict__ b2,
               float* __restrict__ sums, float* __restrict__ counts) {
    __shared__ unsigned int cnt[256];
    __shared__ unsigned int offs[257];
    __shared__ unsigned int cur[256];
    __shared__ unsigned int list[LCAP];      // 24 KB
    __shared__ float w2s[HIDDEN * HIDDEN];   // 4 KB
    __shared__ float accs[GWIN * HIDDEN];    // 2 KB
    __shared__ float cntsl[GWIN];

    int tid = threadIdx.x;
    int bin = blockIdx.x;
    if (tid < 256) cnt[tid] = 0;
    for (int i = tid; i < HIDDEN * HIDDEN; i += 1024) w2s[i] = W2[i];
    if (tid < GWIN * HIDDEN) accs[tid] = 0.f;
    if (tid < GWIN) cntsl[tid] = 0.f;
    __syncthreads();

    int ecount = gcursor[bin] - bin * CAPB;
    if (ecount > LCAP) ecount = LCAP;        // statistically never
    const unsigned int* eb = binned + (size_t)bin * CAPB;

    // pass A: per-node degree histogram (native int LDS atomics)
    for (int e = tid; e < ecount; e += 1024)
        atomicAdd(&cnt[eb[e] >> 16], 1u);
    __syncthreads();

    // pass B: exclusive scan -> offs[0..256]
    if (tid < 256) offs[tid + 1] = cnt[tid];
    if (tid == 0) offs[0] = 0;
    __syncthreads();
    for (int d = 1; d < 256; d <<= 1) {
        unsigned v = 0;
        if (tid < 256) { v = offs[tid + 1]; if (tid >= d) v += offs[tid + 1 - d]; }
        __syncthreads();
        if (tid < 256) offs[tid + 1] = v;
        __syncthreads();
    }
    if (tid < 256) cur[tid] = offs[tid];
    __syncthreads();

    // pass C: placement into per-node CSR lists
    for (int e = tid; e < ecount; e += 1024) {
        unsigned p = eb[e];
        unsigned pos = atomicAdd(&cur[p >> 16], 1u);
        list[pos] = p & 0xFFFFu;
    }
    __syncthreads();

    int node0 = bin << 8;
    int nn = N_NODES - node0; if (nn > 256) nn = 256;
    int g = tid >> 5;      // group 0..31
    int f = tid & 31;      // feature lane
    int gfirst = batch[node0];

    for (int ln = g * 8; ln < g * 8 + 8; ++ln) {
        if (ln >= nn) break;
        int node = node0 + ln;
        float acc = y[(size_t)node * HIDDEN + f];      // self term
        int j = offs[ln], jend = offs[ln + 1];
        for (; j + 4 <= jend; j += 4) {                // 4 y-rows in flight
            unsigned s0 = list[j], s1 = list[j + 1], s2 = list[j + 2], s3 = list[j + 3];
            float a0 = y[(size_t)s0 * HIDDEN + f];
            float a1 = y[(size_t)s1 * HIDDEN + f];
            float a2 = y[(size_t)s2 * HIDDEN + f];
            float a3 = y[(size_t)s3 * HIDDEN + f];
            acc += (a0 + a1) + (a2 + a3);
        }
        for (; j < jend; ++j)
            acc += y[(size_t)list[j] * HIDDEN + f];

        float h1 = fmaxf(acc + b1[f], 0.f);
        // h = ReLU(h1 @ W2 + b2): h1[k] via intra-group shuffle (no LDS round-trip)
        float h2 = b2[f];
#pragma unroll
        for (int k = 0; k < HIDDEN; ++k)
            h2 = fmaf(__shfl(h1, k, 32), w2s[k * HIDDEN + f], h2);
        float h = fmaxf(h2, 0.f);

        int gr = batch[node];
        int b = gr - gfirst;
        if (b < GWIN) {
            atomicAdd(&accs[b * HIDDEN + f], h);       // ~256 adds/block total
            if (f == 0) atomicAdd(&cntsl[b], 1.f);
        } else {
            atomicAdd(&sums[(size_t)gr * HIDDEN + f], h);
            if (f == 0) atomicAdd(&counts[gr], 1.f);
        }
    }
    __syncthreads();

    for (int i = tid; i < GWIN * HIDDEN; i += 1024) {
        float v = accs[i];
        if (v != 0.f) atomicAdd(&sums[(size_t)gfirst * HIDDEN + i], v);
    }
    if (tid < GWIN) {
        float c = cntsl[tid];
        if (c != 0.f) atomicAdd(&counts[gfirst + tid], c);
    }
}

// ---------------------------------------------------------------------------
// Kernel 4: out[g] = (sums[g]/max(counts[g],1)) @ Wc + bc
__global__ void k_out(const float* __restrict__ sums, const float* __restrict__ counts,
                      const float* __restrict__ Wc, const float* __restrict__ bc,
                      float* __restrict__ out) {
    int g = threadIdx.x;
    if (g >= N_GRAPHS) return;
    float inv = 1.f / fmaxf(counts[g], 1.f);
    float o0 = bc[0], o1 = bc[1];
#pragma unroll
    for (int k = 0; k < HIDDEN; ++k) {
        float p = sums[(size_t)g * HIDDEN + k] * inv;
        o0 = fmaf(p, Wc[k * 2 + 0], o0);
        o1 = fmaf(p, Wc[k * 2 + 1], o1);
    }
    out[g * 2 + 0] = o0;
    out[g * 2 + 1] = o1;
}

// ---------------------------------------------------------------------------
extern "C" void kernel_launch(void* const* d_in, const int* in_sizes, int n_in,
                              void* d_out, int out_size, void* d_ws, size_t ws_size,
                              hipStream_t stream) {
    const float* x     = (const float*)d_in[0];
    const int*   ei    = (const int*)d_in[1];   // [2, N_EDGES]: src row then dst row
    const int*   batch = (const int*)d_in[2];
    const float* W1    = (const float*)d_in[3];
    const float* b1    = (const float*)d_in[4];
    const float* W2    = (const float*)d_in[5];
    const float* b2    = (const float*)d_in[6];
    const float* Wc    = (const float*)d_in[7];
    const float* bc    = (const float*)d_in[8];
    float* out = (float*)d_out;

    // Workspace layout (byte offsets):
    //   0        gcursor  NB int      (pad to 1024 B)
    //   1024     sums     8192 f      (32768 B)
    //   33792    counts   256 f       (1024 B)
    //   34816    binned   NB*CAPB u32 (6422528 B)
    //   6457344  y        1.6M f      (6400000 B)
    char* ws = (char*)d_ws;
    int*          gcursor = (int*)ws;
    float*        sums    = (float*)(ws + 1024);
    float*        counts  = (float*)(ws + 33792);
    unsigned int* binned  = (unsigned int*)(ws + 34816);
    float*        y       = (float*)(ws + 6457344);

    k_xw1<<<N_NODES * HIDDEN / 256, 256, 0, stream>>>(x, W1, y, gcursor, sums, counts);

    k_partition<<<PB, 256, 0, stream>>>(ei, ei + N_EDGES, gcursor, binned);

    k_agg_mlp_pool<<<NB, 1024, 0, stream>>>(binned, gcursor, y, batch,
                                            b1, W2, b2, sums, counts);

    k_out<<<1, 256, 0, stream>>>(sums, counts, Wc, bc, out);
}